// Round 1
// baseline (188.814 us; speedup 1.0000x reference)
//
#include <hip/hip_runtime.h>

#define T_TOK 4096
#define H_DIM 1024
#define I_DIM 512
#define E_EXP 16
#define BM    128
#define BK    64
#define BSTR  68   // Bs row stride in shorts (64 + 4 pad)

using bf16x8   = __attribute__((ext_vector_type(8))) short;
using floatx4  = __attribute__((ext_vector_type(4))) float;
using ushort4v = __attribute__((ext_vector_type(4))) unsigned short;

__device__ __forceinline__ unsigned short f2bf(float f) {
  union { float f; unsigned u; } v; v.f = f;
  return (unsigned short)((v.u + 0x7FFFu + ((v.u >> 16) & 1u)) >> 16);  // RNE
}
__device__ __forceinline__ unsigned pk2(float a, float b) {
  return (unsigned)f2bf(a) | ((unsigned)f2bf(b) << 16);
}

__device__ __forceinline__ void gld16(const void* g, void* l) {
  __builtin_amdgcn_global_load_lds((const __attribute__((address_space(1))) void*)g,
                                   (__attribute__((address_space(3))) void*)l,
                                   16, 0, 0);
}

__device__ __forceinline__ bool tile_info(const int* __restrict__ counts, int by,
                                          int& e, int& row0, int& base, int& cnt) {
  int acc = 0, off = 0;
  e = -1;
  #pragma unroll
  for (int i = 0; i < E_EXP; ++i) {
    int c = counts[i];
    int nt = (c + BM - 1) >> 7;
    if (e < 0 && by < acc + nt) { e = i; row0 = (by - acc) * BM; base = off; cnt = c; }
    acc += nt; off += c;
  }
  return e >= 0;
}

// ---------------- x: fp32 -> bf16 (streaming) ----------------
__global__ void k_cvt(const float* __restrict__ x, unsigned short* __restrict__ xb) {
  const float4* s4 = (const float4*)x;
  int b0 = blockIdx.x * 512 + threadIdx.x;
  float4 a = s4[b0];
  float4 b = s4[b0 + 256];
  ushort4v oa, ob;
  oa.x = f2bf(a.x); oa.y = f2bf(a.y); oa.z = f2bf(a.z); oa.w = f2bf(a.w);
  ob.x = f2bf(b.x); ob.y = f2bf(b.y); ob.z = f2bf(b.z); ob.w = f2bf(b.w);
  ((ushort4v*)xb)[b0] = oa;
  ((ushort4v*)xb)[b0 + 256] = ob;
}

// ---------------- GEMM A: h = silu(x@Wg)*(x@Wu) ----------------
// Depth-1 pipeline: prefetch B(t+1)->regs + gld16 A(t+1)->As[nxt] BEFORE compute(t).
// As double-buffered (gld16 path), Bs single-buffered (reg-staged, written post-barrier).
// A-tile 16B-chunk XOR swizzle (chunk ^= row&7): pre-swizzled global source (gld16 dest
// must be linear, m104/m173) + swizzled ds_read -> 16-way bank conflict becomes 2-way.
__launch_bounds__(256, 3)
__global__ void k_gemm_a(const unsigned short* __restrict__ xb,
                         const float* __restrict__ wgu,
                         unsigned short* __restrict__ hb,
                         const int* __restrict__ counts) {
  __shared__ unsigned short As[2][BM * BK];   // 2 x 16 KB
  __shared__ unsigned short Bs[BM * BSTR];    // 17 KB; rows 0-63 g, 64-127 u

  int e, row0, base, cnt;
  if (!tile_info(counts, blockIdx.y, e, row0, base, cnt)) return;
  const int rows = (cnt - row0 < BM) ? (cnt - row0) : BM;
  const int c0 = blockIdx.x * 64;

  const int tid = threadIdx.x;
  const int w = tid >> 6, l = tid & 63;
  const int lr = l & 15, q = l >> 4;
  const int asr = l >> 3;                     // LDS slot row within 8-row group
  const int akc = ((l & 7) ^ asr) * 8;        // XOR-swizzled global 16B-chunk (shorts)
  const int cswz = lr & 7;                    // read-side swizzle key
  // B staging: this thread owns one transposed LDS row (column of W)
  const int nloc = ((w & 1) << 6) | l;        // 0..127
  const int kh = (w >> 1) * 32;               // k-half within BK
  const int gcol = (nloc < 64) ? (c0 + nloc) : (I_DIM + c0 + (nloc - 64));
  const float* wcol = wgu + (size_t)e * H_DIM * (2 * I_DIM) + gcol;
  unsigned int* BsD = (unsigned int*)Bs;
  const int bdst = nloc * (BSTR / 2) + (kh >> 1);

  const int mhalf = w & 1, nhalf = w >> 1;
  const int mrow = mhalf * 64;
  const unsigned short* arow = xb + (size_t)(base + row0) * H_DIM;

  int agr[4];
  #pragma unroll
  for (int t = 0; t < 4; ++t) {
    int r = w * 32 + t * 8 + asr;
    agr[t] = (r < rows) ? r : rows - 1;
  }

  floatx4 accg[4][2], accu[4][2];
  #pragma unroll
  for (int i = 0; i < 4; ++i)
    #pragma unroll
    for (int j = 0; j < 2; ++j) { accg[i][j] = (floatx4){0,0,0,0}; accu[i][j] = (floatx4){0,0,0,0}; }

  float bv[32];

  // ---- prologue: stage tile 0 ----
  #pragma unroll
  for (int j = 0; j < 32; ++j) bv[j] = wcol[(size_t)(kh + j) * (2 * I_DIM)];
  #pragma unroll
  for (int t = 0; t < 4; ++t)
    gld16(&arow[(size_t)agr[t] * H_DIM + akc], &As[0][(w * 32 + t * 8) * BK]);
  #pragma unroll
  for (int jq = 0; jq < 8; ++jq) {
    uint2 d;
    d.x = pk2(bv[4 * jq + 0], bv[4 * jq + 1]);
    d.y = pk2(bv[4 * jq + 2], bv[4 * jq + 3]);
    *(uint2*)&BsD[bdst + jq * 2] = d;
  }
  __syncthreads();

  auto compute = [&](int cb) {
    #pragma unroll
    for (int kf = 0; kf < 2; ++kf) {
      const int c = kf * 4 + q;
      const int ca = (c ^ cswz) * 8;          // swizzled A chunk
      const int ch = c * 8;                   // linear B chunk
      bf16x8 af[4], bg[2], bu[2];
      #pragma unroll
      for (int mi = 0; mi < 4; ++mi)
        af[mi] = *(const bf16x8*)&As[cb][(mrow + mi * 16 + lr) * BK + ca];
      #pragma unroll
      for (int ni = 0; ni < 2; ++ni) {
        bg[ni] = *(const bf16x8*)&Bs[(nhalf * 32 + ni * 16 + lr) * BSTR + ch];
        bu[ni] = *(const bf16x8*)&Bs[(64 + nhalf * 32 + ni * 16 + lr) * BSTR + ch];
      }
      #pragma unroll
      for (int mi = 0; mi < 4; ++mi)
        #pragma unroll
        for (int ni = 0; ni < 2; ++ni) {
          accg[mi][ni] = __builtin_amdgcn_mfma_f32_16x16x32_bf16(af[mi], bg[ni], accg[mi][ni], 0, 0, 0);
          accu[mi][ni] = __builtin_amdgcn_mfma_f32_16x16x32_bf16(af[mi], bu[ni], accu[mi][ni], 0, 0, 0);
        }
    }
  };

  const int nk = H_DIM / BK;   // 16
  int cur = 0;
  for (int ki = 0; ki < nk - 1; ++ki) {
    const int kk = (ki + 1) * BK;
    // prefetch next tile: B -> regs, A -> As[cur^1] (flies under the MFMAs below)
    #pragma unroll
    for (int j = 0; j < 32; ++j) bv[j] = wcol[(size_t)(kk + kh + j) * (2 * I_DIM)];
    #pragma unroll
    for (int t = 0; t < 4; ++t)
      gld16(&arow[(size_t)agr[t] * H_DIM + kk + akc], &As[cur ^ 1][(w * 32 + t * 8) * BK]);
    compute(cur);
    __syncthreads();            // all waves done reading Bs; drains vmcnt for prefetch
    #pragma unroll
    for (int jq = 0; jq < 8; ++jq) {
      uint2 d;
      d.x = pk2(bv[4 * jq + 0], bv[4 * jq + 1]);
      d.y = pk2(bv[4 * jq + 2], bv[4 * jq + 3]);
      *(uint2*)&BsD[bdst + jq * 2] = d;
    }
    __syncthreads();            // Bs(t+1) + As[nxt] visible
    cur ^= 1;
  }
  compute(cur);                 // tail tile

  #pragma unroll
  for (int mi = 0; mi < 4; ++mi)
    #pragma unroll
    for (int r = 0; r < 4; ++r) {
      int row_local = mrow + mi * 16 + q * 4 + r;
      if (row_local >= rows) continue;
      size_t orow = (size_t)(base + row0 + row_local) * I_DIM;
      #pragma unroll
      for (int ni = 0; ni < 2; ++ni) {
        float g = accg[mi][ni][r], u = accu[mi][ni][r];
        float s = g / (1.0f + __expf(-g)) * u;
        hb[orow + c0 + nhalf * 32 + ni * 16 + lr] = f2bf(s);
      }
    }
}

// ---------------- GEMM B: out = h @ Wd (same pipeline structure) ----------------
__launch_bounds__(256, 3)
__global__ void k_gemm_b(const unsigned short* __restrict__ hb,
                         const float* __restrict__ wdn,
                         float* __restrict__ out,
                         const int* __restrict__ counts) {
  __shared__ unsigned short As[2][BM * BK];
  __shared__ unsigned short Bs[BM * BSTR];

  int e, row0, base, cnt;
  if (!tile_info(counts, blockIdx.y, e, row0, base, cnt)) return;
  const int rows = (cnt - row0 < BM) ? (cnt - row0) : BM;
  const int n0 = blockIdx.x * 128;

  const int tid = threadIdx.x;
  const int w = tid >> 6, l = tid & 63;
  const int lr = l & 15, q = l >> 4;
  const int asr = l >> 3;
  const int akc = ((l & 7) ^ asr) * 8;
  const int cswz = lr & 7;
  const int nloc = ((w & 1) << 6) | l;
  const int kh = (w >> 1) * 32;
  const float* wcol = wdn + (size_t)e * I_DIM * H_DIM + n0 + nloc;
  unsigned int* BsD = (unsigned int*)Bs;
  const int bdst = nloc * (BSTR / 2) + (kh >> 1);

  const int mhalf = w & 1, nhalf = w >> 1;
  const int mrow = mhalf * 64;
  const unsigned short* arow = hb + (size_t)(base + row0) * I_DIM;

  int agr[4];
  #pragma unroll
  for (int t = 0; t < 4; ++t) {
    int r = w * 32 + t * 8 + asr;
    agr[t] = (r < rows) ? r : rows - 1;
  }

  floatx4 acc[4][4];
  #pragma unroll
  for (int i = 0; i < 4; ++i)
    #pragma unroll
    for (int j = 0; j < 4; ++j) acc[i][j] = (floatx4){0,0,0,0};

  float bv[32];

  // ---- prologue: stage tile 0 ----
  #pragma unroll
  for (int j = 0; j < 32; ++j) bv[j] = wcol[(size_t)(kh + j) * H_DIM];
  #pragma unroll
  for (int t = 0; t < 4; ++t)
    gld16(&arow[(size_t)agr[t] * I_DIM + akc], &As[0][(w * 32 + t * 8) * BK]);
  #pragma unroll
  for (int jq = 0; jq < 8; ++jq) {
    uint2 d;
    d.x = pk2(bv[4 * jq + 0], bv[4 * jq + 1]);
    d.y = pk2(bv[4 * jq + 2], bv[4 * jq + 3]);
    *(uint2*)&BsD[bdst + jq * 2] = d;
  }
  __syncthreads();

  auto compute = [&](int cb) {
    #pragma unroll
    for (int kf = 0; kf < 2; ++kf) {
      const int c = kf * 4 + q;
      const int ca = (c ^ cswz) * 8;
      const int ch = c * 8;
      bf16x8 af[4], bf[4];
      #pragma unroll
      for (int mi = 0; mi < 4; ++mi)
        af[mi] = *(const bf16x8*)&As[cb][(mrow + mi * 16 + lr) * BK + ca];
      #pragma unroll
      for (int ni = 0; ni < 4; ++ni)
        bf[ni] = *(const bf16x8*)&Bs[(nhalf * 64 + ni * 16 + lr) * BSTR + ch];
      #pragma unroll
      for (int mi = 0; mi < 4; ++mi)
        #pragma unroll
        for (int ni = 0; ni < 4; ++ni)
          acc[mi][ni] = __builtin_amdgcn_mfma_f32_16x16x32_bf16(af[mi], bf[ni], acc[mi][ni], 0, 0, 0);
    }
  };

  const int nk = I_DIM / BK;   // 8
  int cur = 0;
  for (int ki = 0; ki < nk - 1; ++ki) {
    const int kk = (ki + 1) * BK;
    #pragma unroll
    for (int j = 0; j < 32; ++j) bv[j] = wcol[(size_t)(kk + kh + j) * H_DIM];
    #pragma unroll
    for (int t = 0; t < 4; ++t)
      gld16(&arow[(size_t)agr[t] * I_DIM + kk + akc], &As[cur ^ 1][(w * 32 + t * 8) * BK]);
    compute(cur);
    __syncthreads();
    #pragma unroll
    for (int jq = 0; jq < 8; ++jq) {
      uint2 d;
      d.x = pk2(bv[4 * jq + 0], bv[4 * jq + 1]);
      d.y = pk2(bv[4 * jq + 2], bv[4 * jq + 3]);
      *(uint2*)&BsD[bdst + jq * 2] = d;
    }
    __syncthreads();
    cur ^= 1;
  }
  compute(cur);

  #pragma unroll
  for (int mi = 0; mi < 4; ++mi)
    #pragma unroll
    for (int r = 0; r < 4; ++r) {
      int row_local = mrow + mi * 16 + q * 4 + r;
      if (row_local >= rows) continue;
      size_t orow = (size_t)(base + row0 + row_local) * H_DIM;
      #pragma unroll
      for (int ni = 0; ni < 4; ++ni)
        out[orow + n0 + nhalf * 64 + ni * 16 + lr] = acc[mi][ni][r];
    }
}

// ---------------- launch ----------------
extern "C" void kernel_launch(void* const* d_in, const int* in_sizes, int n_in,
                              void* d_out, int out_size, void* d_ws, size_t ws_size,
                              hipStream_t stream) {
  const float* x      = (const float*)d_in[0];
  const float* wgu    = (const float*)d_in[1];
  const float* wdn    = (const float*)d_in[2];
  const int*   counts = (const int*)d_in[3];
  float* out = (float*)d_out;

  unsigned char* ws = (unsigned char*)d_ws;
  unsigned short* xb = (unsigned short*)(ws);            // 8 MB
  unsigned short* hb = (unsigned short*)(ws + 8388608);  // 4 MB

  k_cvt<<<2048, 256, 0, stream>>>(x, xb);
  k_gemm_a<<<dim3(I_DIM / 64, 48), 256, 0, stream>>>(xb, wgu, hb, counts);
  k_gemm_b<<<dim3(H_DIM / 128, 48), 256, 0, stream>>>(hb, wdn, out, counts);
}

// Round 2
// 178.587 us; speedup vs baseline: 1.0573x; 1.0573x over previous
//
#include <hip/hip_runtime.h>

#define T_TOK 4096
#define H_DIM 1024
#define I_DIM 512
#define E_EXP 16
#define BM    128
#define BK    64
#define BSTR  68   // Bs row stride in shorts (64 + 4 pad)

using bf16x8   = __attribute__((ext_vector_type(8))) short;
using floatx4  = __attribute__((ext_vector_type(4))) float;
using ushort4v = __attribute__((ext_vector_type(4))) unsigned short;

__device__ __forceinline__ unsigned short f2bf(float f) {
  union { float f; unsigned u; } v; v.f = f;
  return (unsigned short)((v.u + 0x7FFFu + ((v.u >> 16) & 1u)) >> 16);  // RNE
}
__device__ __forceinline__ unsigned pk2(float a, float b) {
  return (unsigned)f2bf(a) | ((unsigned)f2bf(b) << 16);
}

__device__ __forceinline__ void gld16(const void* g, void* l) {
  __builtin_amdgcn_global_load_lds((const __attribute__((address_space(1))) void*)g,
                                   (__attribute__((address_space(3))) void*)l,
                                   16, 0, 0);
}

// barrier with ONLY lgkm drained (vmem prefetch stays in flight across it)
__device__ __forceinline__ void bar_lgkm() {
  asm volatile("s_waitcnt lgkmcnt(0)" ::: "memory");
  __builtin_amdgcn_sched_barrier(0);
  __builtin_amdgcn_s_barrier();
  __builtin_amdgcn_sched_barrier(0);
}
// barrier with full drain (vmem + lgkm) — once per K-step
__device__ __forceinline__ void bar_full() {
  asm volatile("s_waitcnt vmcnt(0) lgkmcnt(0)" ::: "memory");
  __builtin_amdgcn_sched_barrier(0);
  __builtin_amdgcn_s_barrier();
  __builtin_amdgcn_sched_barrier(0);
}

__device__ __forceinline__ bool tile_info(const int* __restrict__ counts, int by,
                                          int& e, int& row0, int& base, int& cnt) {
  int acc = 0, off = 0;
  e = -1;
  #pragma unroll
  for (int i = 0; i < E_EXP; ++i) {
    int c = counts[i];
    int nt = (c + BM - 1) >> 7;
    if (e < 0 && by < acc + nt) { e = i; row0 = (by - acc) * BM; base = off; cnt = c; }
    acc += nt; off += c;
  }
  return e >= 0;
}

// ---------------- x: fp32 -> bf16 (streaming) ----------------
__global__ void k_cvt(const float* __restrict__ x, unsigned short* __restrict__ xb) {
  const float4* s4 = (const float4*)x;
  int b0 = blockIdx.x * 512 + threadIdx.x;
  float4 a = s4[b0];
  float4 b = s4[b0 + 256];
  ushort4v oa, ob;
  oa.x = f2bf(a.x); oa.y = f2bf(a.y); oa.z = f2bf(a.z); oa.w = f2bf(a.w);
  ob.x = f2bf(b.x); ob.y = f2bf(b.y); ob.z = f2bf(b.z); ob.w = f2bf(b.w);
  ((ushort4v*)xb)[b0] = oa;
  ((ushort4v*)xb)[b0 + 256] = ob;
}

// ---------------- GEMM A: h = silu(x@Wg)*(x@Wu) ----------------
// B staging: thread (kb = tid>>5, nb = tid&31) loads 8 x float4 = rows kb*8..+7,
// cols 4nb..4nb+3 of the W tile — coalesced 16B/lane, ONE latency batch.
// Pipeline per K-step: issue B(t+1)+A(t+1) vmem -> compute(t) -> bar_lgkm
// (vmem in flight) -> convert+ds_write Bs(t+1) -> bar_full -> flip.
__launch_bounds__(256, 3)
__global__ void k_gemm_a(const unsigned short* __restrict__ xb,
                         const float* __restrict__ wgu,
                         unsigned short* __restrict__ hb,
                         const int* __restrict__ counts) {
  __shared__ unsigned short As[2][BM * BK];   // 2 x 16 KB
  __shared__ unsigned short Bs[BM * BSTR];    // 17 KB; rows 0-63 g, 64-127 u

  int e, row0, base, cnt;
  if (!tile_info(counts, blockIdx.y, e, row0, base, cnt)) return;
  const int rows = (cnt - row0 < BM) ? (cnt - row0) : BM;
  const int c0 = blockIdx.x * 64;

  const int tid = threadIdx.x;
  const int w = tid >> 6, l = tid & 63;
  const int lr = l & 15, q = l >> 4;
  const int asr = l >> 3;                     // A staging: LDS slot row in 8-row group
  const int akc = ((l & 7) ^ asr) * 8;        // XOR-swizzled global 16B chunk (shorts)
  const int cswz = lr & 7;                    // A read-side swizzle key

  // B staging coords
  const int nl4 = (tid & 31) * 4;             // tile-col base 0..124
  const int kb8 = (tid >> 5) * 8;             // k base 0..56
  const int gc4 = (nl4 < 64) ? (c0 + nl4) : (I_DIM + c0 + nl4 - 64);
  const float* wmat = wgu + (size_t)e * H_DIM * (2 * I_DIM) + gc4;
  unsigned int* BsD = (unsigned int*)Bs;
  const int bd0 = nl4 * (BSTR / 2) + (kb8 >> 1);  // dword index of (row nl4, k kb8)

  const int mhalf = w & 1, nhalf = w >> 1;
  const int mrow = mhalf * 64;
  const unsigned short* arow = xb + (size_t)(base + row0) * H_DIM;

  int agr[4];
  #pragma unroll
  for (int t = 0; t < 4; ++t) {
    int r = w * 32 + t * 8 + asr;
    agr[t] = (r < rows) ? r : rows - 1;
  }

  floatx4 accg[4][2], accu[4][2];
  #pragma unroll
  for (int i = 0; i < 4; ++i)
    #pragma unroll
    for (int j = 0; j < 2; ++j) { accg[i][j] = (floatx4){0,0,0,0}; accu[i][j] = (floatx4){0,0,0,0}; }

  float4 bv4[8];

  auto loadB = [&](int kk) {
    #pragma unroll
    for (int j = 0; j < 8; ++j)
      bv4[j] = *(const float4*)&wmat[(size_t)(kk + kb8 + j) * (2 * I_DIM)];
  };
  auto loadA = [&](int kk, int buf) {
    #pragma unroll
    for (int t = 0; t < 4; ++t)
      gld16(&arow[(size_t)agr[t] * H_DIM + kk + akc], &As[buf][(w * 32 + t * 8) * BK]);
  };
  auto writeB = [&]() {
    #pragma unroll
    for (int c = 0; c < 4; ++c) {
      uint2 d0, d1;
      d0.x = pk2(bv4[0][c], bv4[1][c]); d0.y = pk2(bv4[2][c], bv4[3][c]);
      d1.x = pk2(bv4[4][c], bv4[5][c]); d1.y = pk2(bv4[6][c], bv4[7][c]);
      *(uint2*)&BsD[bd0 + c * (BSTR / 2)]     = d0;
      *(uint2*)&BsD[bd0 + c * (BSTR / 2) + 2] = d1;
    }
  };
  auto compute = [&](int cb) {
    #pragma unroll
    for (int kf = 0; kf < 2; ++kf) {
      const int c = kf * 4 + q;
      const int ca = (c ^ cswz) * 8;          // swizzled A chunk
      const int ch = c * 8;                   // linear B chunk
      bf16x8 af[4], bg[2], bu[2];
      #pragma unroll
      for (int mi = 0; mi < 4; ++mi)
        af[mi] = *(const bf16x8*)&As[cb][(mrow + mi * 16 + lr) * BK + ca];
      #pragma unroll
      for (int ni = 0; ni < 2; ++ni) {
        bg[ni] = *(const bf16x8*)&Bs[(nhalf * 32 + ni * 16 + lr) * BSTR + ch];
        bu[ni] = *(const bf16x8*)&Bs[(64 + nhalf * 32 + ni * 16 + lr) * BSTR + ch];
      }
      #pragma unroll
      for (int mi = 0; mi < 4; ++mi)
        #pragma unroll
        for (int ni = 0; ni < 2; ++ni) {
          accg[mi][ni] = __builtin_amdgcn_mfma_f32_16x16x32_bf16(af[mi], bg[ni], accg[mi][ni], 0, 0, 0);
          accu[mi][ni] = __builtin_amdgcn_mfma_f32_16x16x32_bf16(af[mi], bu[ni], accu[mi][ni], 0, 0, 0);
        }
    }
  };

  // ---- prologue: stage tile 0 (full drain is fine once) ----
  loadB(0);
  loadA(0, 0);
  writeB();
  __syncthreads();

  const int nk = H_DIM / BK;   // 16
  int cur = 0;
  for (int ki = 0; ki < nk - 1; ++ki) {
    const int kk = (ki + 1) * BK;
    loadB(kk);                  // vmem, one batch
    loadA(kk, cur ^ 1);         // gld16 -> other buffer
    __builtin_amdgcn_sched_barrier(0);   // keep prefetch above compute
    compute(cur);
    bar_lgkm();                 // Bs reads done everywhere; prefetch still flying
    writeB();                   // compiler waits counted vmcnt for bv4 use
    bar_full();                 // Bs(t+1) + As[nxt] visible
    cur ^= 1;
  }
  compute(cur);                 // tail

  #pragma unroll
  for (int mi = 0; mi < 4; ++mi)
    #pragma unroll
    for (int r = 0; r < 4; ++r) {
      int row_local = mrow + mi * 16 + q * 4 + r;
      if (row_local >= rows) continue;
      size_t orow = (size_t)(base + row0 + row_local) * I_DIM;
      #pragma unroll
      for (int ni = 0; ni < 2; ++ni) {
        float g = accg[mi][ni][r], u = accu[mi][ni][r];
        float s = g / (1.0f + __expf(-g)) * u;
        hb[orow + c0 + nhalf * 32 + ni * 16 + lr] = f2bf(s);
      }
    }
}

// ---------------- GEMM B: out = h @ Wd (same structure) ----------------
__launch_bounds__(256, 3)
__global__ void k_gemm_b(const unsigned short* __restrict__ hb,
                         const float* __restrict__ wdn,
                         float* __restrict__ out,
                         const int* __restrict__ counts) {
  __shared__ unsigned short As[2][BM * BK];
  __shared__ unsigned short Bs[BM * BSTR];

  int e, row0, base, cnt;
  if (!tile_info(counts, blockIdx.y, e, row0, base, cnt)) return;
  const int rows = (cnt - row0 < BM) ? (cnt - row0) : BM;
  const int n0 = blockIdx.x * 128;

  const int tid = threadIdx.x;
  const int w = tid >> 6, l = tid & 63;
  const int lr = l & 15, q = l >> 4;
  const int asr = l >> 3;
  const int akc = ((l & 7) ^ asr) * 8;
  const int cswz = lr & 7;

  const int nl4 = (tid & 31) * 4;
  const int kb8 = (tid >> 5) * 8;
  const float* wmat = wdn + (size_t)e * I_DIM * H_DIM + n0 + nl4;
  unsigned int* BsD = (unsigned int*)Bs;
  const int bd0 = nl4 * (BSTR / 2) + (kb8 >> 1);

  const int mhalf = w & 1, nhalf = w >> 1;
  const int mrow = mhalf * 64;
  const unsigned short* arow = hb + (size_t)(base + row0) * I_DIM;

  int agr[4];
  #pragma unroll
  for (int t = 0; t < 4; ++t) {
    int r = w * 32 + t * 8 + asr;
    agr[t] = (r < rows) ? r : rows - 1;
  }

  floatx4 acc[4][4];
  #pragma unroll
  for (int i = 0; i < 4; ++i)
    #pragma unroll
    for (int j = 0; j < 4; ++j) acc[i][j] = (floatx4){0,0,0,0};

  float4 bv4[8];

  auto loadB = [&](int kk) {
    #pragma unroll
    for (int j = 0; j < 8; ++j)
      bv4[j] = *(const float4*)&wmat[(size_t)(kk + kb8 + j) * H_DIM];
  };
  auto loadA = [&](int kk, int buf) {
    #pragma unroll
    for (int t = 0; t < 4; ++t)
      gld16(&arow[(size_t)agr[t] * I_DIM + kk + akc], &As[buf][(w * 32 + t * 8) * BK]);
  };
  auto writeB = [&]() {
    #pragma unroll
    for (int c = 0; c < 4; ++c) {
      uint2 d0, d1;
      d0.x = pk2(bv4[0][c], bv4[1][c]); d0.y = pk2(bv4[2][c], bv4[3][c]);
      d1.x = pk2(bv4[4][c], bv4[5][c]); d1.y = pk2(bv4[6][c], bv4[7][c]);
      *(uint2*)&BsD[bd0 + c * (BSTR / 2)]     = d0;
      *(uint2*)&BsD[bd0 + c * (BSTR / 2) + 2] = d1;
    }
  };
  auto compute = [&](int cb) {
    #pragma unroll
    for (int kf = 0; kf < 2; ++kf) {
      const int c = kf * 4 + q;
      const int ca = (c ^ cswz) * 8;
      const int ch = c * 8;
      bf16x8 af[4], bf[4];
      #pragma unroll
      for (int mi = 0; mi < 4; ++mi)
        af[mi] = *(const bf16x8*)&As[cb][(mrow + mi * 16 + lr) * BK + ca];
      #pragma unroll
      for (int ni = 0; ni < 4; ++ni)
        bf[ni] = *(const bf16x8*)&Bs[(nhalf * 64 + ni * 16 + lr) * BSTR + ch];
      #pragma unroll
      for (int mi = 0; mi < 4; ++mi)
        #pragma unroll
        for (int ni = 0; ni < 4; ++ni)
          acc[mi][ni] = __builtin_amdgcn_mfma_f32_16x16x32_bf16(af[mi], bf[ni], acc[mi][ni], 0, 0, 0);
    }
  };

  loadB(0);
  loadA(0, 0);
  writeB();
  __syncthreads();

  const int nk = I_DIM / BK;   // 8
  int cur = 0;
  for (int ki = 0; ki < nk - 1; ++ki) {
    const int kk = (ki + 1) * BK;
    loadB(kk);
    loadA(kk, cur ^ 1);
    __builtin_amdgcn_sched_barrier(0);
    compute(cur);
    bar_lgkm();
    writeB();
    bar_full();
    cur ^= 1;
  }
  compute(cur);

  #pragma unroll
  for (int mi = 0; mi < 4; ++mi)
    #pragma unroll
    for (int r = 0; r < 4; ++r) {
      int row_local = mrow + mi * 16 + q * 4 + r;
      if (row_local >= rows) continue;
      size_t orow = (size_t)(base + row0 + row_local) * H_DIM;
      #pragma unroll
      for (int ni = 0; ni < 4; ++ni)
        out[orow + n0 + nhalf * 64 + ni * 16 + lr] = acc[mi][ni][r];
    }
}

// ---------------- launch ----------------
extern "C" void kernel_launch(void* const* d_in, const int* in_sizes, int n_in,
                              void* d_out, int out_size, void* d_ws, size_t ws_size,
                              hipStream_t stream) {
  const float* x      = (const float*)d_in[0];
  const float* wgu    = (const float*)d_in[1];
  const float* wdn    = (const float*)d_in[2];
  const int*   counts = (const int*)d_in[3];
  float* out = (float*)d_out;

  unsigned char* ws = (unsigned char*)d_ws;
  unsigned short* xb = (unsigned short*)(ws);            // 8 MB
  unsigned short* hb = (unsigned short*)(ws + 8388608);  // 4 MB

  k_cvt<<<2048, 256, 0, stream>>>(x, xb);
  k_gemm_a<<<dim3(I_DIM / 64, 48), 256, 0, stream>>>(xb, wgu, hb, counts);
  k_gemm_b<<<dim3(H_DIM / 128, 48), 256, 0, stream>>>(hb, wdn, out, counts);
}